// Round 3
// baseline (88.544 us; speedup 1.0000x reference)
//
#include <hip/hip_runtime.h>
#include <hip/hip_bf16.h>
#include <math.h>

typedef float f4 __attribute__((ext_vector_type(4)));
typedef float f32x4 __attribute__((ext_vector_type(4)));
typedef short s8v __attribute__((ext_vector_type(8)));
typedef unsigned short u16;
typedef u16 u16x4 __attribute__((ext_vector_type(4)));

#define TT 2048
#define CC 768
#define HH 64
#define NB 8
#define NBT (NB * TT)
#define NQ (NBT * HH)
#define QSCALE 0.18033688011112042f   // 0.125 * log2(e): softmax in base-2 domain

__device__ __forceinline__ u16 f2bf(float f) {
  unsigned u = __float_as_uint(f);
  u = (u + 0x7fffu + ((u >> 16) & 1u)) >> 16;
  return (u16)u;
}
__device__ __forceinline__ float bf2f(u16 v) {
  return __uint_as_float(((unsigned)v) << 16);
}
__device__ __forceinline__ u16x4 pack4(f32x4 v) {
  union { u16x4 u; __hip_bfloat162 h[2]; } r;
  r.h[0] = __float22bfloat162_rn(make_float2(v[0], v[1]));
  r.h[1] = __float22bfloat162_rn(make_float2(v[2], v[3]));
  return r.u;
}
__device__ __forceinline__ s8v pack8(f4 lo, f4 hi) {
  union { s8v s; __hip_bfloat162 h[4]; } r;
  r.h[0] = __float22bfloat162_rn(make_float2(lo.x, lo.y));
  r.h[1] = __float22bfloat162_rn(make_float2(lo.z, lo.w));
  r.h[2] = __float22bfloat162_rn(make_float2(hi.x, hi.y));
  r.h[3] = __float22bfloat162_rn(make_float2(hi.z, hi.w));
  return r.s;
}

#define MFMA16(a, b, c) __builtin_amdgcn_mfma_f32_16x16x32_bf16(a, b, c, 0, 0, 0)

// ---------------------------------------------------------------------------
// Kernel 0: W -> bf16 transposed: wt[c][kc]; c: 0..63=q, 64..127=k, 128..191=v
// ---------------------------------------------------------------------------
__global__ __launch_bounds__(256) void prep_w(
    const float* __restrict__ Wk, const float* __restrict__ Wq,
    const float* __restrict__ Wv, u16* __restrict__ wt) {
  int idx = blockIdx.x * 256 + threadIdx.x;
  int c = idx / CC, kc = idx % CC;
  const float* Wm = (c < 64) ? Wq : (c < 128) ? Wk : Wv;
  wt[idx] = f2bf(Wm[kc * HH + (c & 63)]);
}

// ---------------------------------------------------------------------------
// Kernel 1: QKV projection. 256 blocks x 256 thr; 4 waves x (16 rows x 192 c).
// x: global->reg (read once). W: K=128 chunks, double-buffered swizzled LDS
// via global_load_lds (pre-swizzled source, linear dest). No fp32 MFMA exists;
// inputs cast to bf16. q output pre-scaled by 0.125*log2e.
// ---------------------------------------------------------------------------
__global__ __launch_bounds__(256) void qkv_proj(
    const float* __restrict__ x, const u16* __restrict__ wt,
    u16* __restrict__ qb, u16* __restrict__ kb, u16* __restrict__ vt) {
  __shared__ char lds[98304];   // 2 x 48KB (192 cols x 128 k x bf16)
  const int tid = threadIdx.x;
  const int wv = tid >> 6, lane = tid & 63;
  const int g = lane >> 4, t16 = lane & 15;
  const int row0 = blockIdx.x * 64;
  const int myrow = row0 + wv * 16 + t16;

  f32x4 zz = {0.f, 0.f, 0.f, 0.f};
  f32x4 acc[12];
#pragma unroll
  for (int cf = 0; cf < 12; ++cf) acc[cf] = zz;

  auto stage = [&](int buf, int kt) {
    int k0 = kt * 128;
#pragma unroll
    for (int n = 0; n < 12; ++n) {
      int e = n * 256 + tid;            // 0..3071 16B units
      int col = e >> 4, kb16 = e & 15;
      int sbyte = (kb16 * 16) ^ ((col & 7) << 4);   // inverse-swizzled source
      const u16* src = wt + (size_t)col * CC + k0 + (sbyte >> 1);
      char* dst = lds + buf * 49152 + n * 4096 + wv * 1024;
      __builtin_amdgcn_global_load_lds((const unsigned int*)src,
                                       (unsigned int*)dst, 16, 0, 0);
    }
  };

  stage(0, 0);
  asm volatile("s_waitcnt vmcnt(0)" ::: "memory");
  __syncthreads();

  for (int kt = 0; kt < 6; ++kt) {
    int buf = kt & 1;
    if (kt < 5) stage(buf ^ 1, kt + 1);   // prefetch overlaps compute
    int k0 = kt * 128;
#pragma unroll
    for (int s = 0; s < 4; ++s) {
      const f4* xp = (const f4*)(x + (size_t)myrow * CC + k0 + s * 32 + g * 8);
      f4 lo = xp[0], hi = xp[1];
      s8v a = pack8(lo, hi);
#pragma unroll
      for (int cf = 0; cf < 12; ++cf) {
        int col = cf * 16 + t16;
        int off = buf * 49152 +
                  ((col * 256 + s * 64 + g * 16) ^ ((t16 & 7) << 4));
        s8v b = *(const s8v*)(lds + off);
        acc[cf] = MFMA16(a, b, acc[cf]);
      }
    }
    asm volatile("s_waitcnt vmcnt(0)" ::: "memory");
    __syncthreads();
  }

  // epilogue: D row = g*4+r, col = t16 (m89-verified layout)
  const int rb = row0 + wv * 16 + g * 4;
#pragma unroll
  for (int cf = 0; cf < 12; ++cf) {
    int col = cf * 16 + t16;
    int m = col >> 6, h = col & 63;
    if (m == 0) {
#pragma unroll
      for (int r = 0; r < 4; ++r)
        qb[(size_t)(rb + r) * HH + h] = f2bf(acc[cf][r] * QSCALE);
    } else if (m == 1) {
#pragma unroll
      for (int r = 0; r < 4; ++r)
        kb[(size_t)(rb + r) * HH + h] = f2bf(acc[cf][r]);
    } else {
      int bbi = rb >> 11;
      u16x4 pk = pack4(acc[cf]);
      *(u16x4*)(vt + (size_t)(bbi * 64 + h) * TT + (rb & 2047)) = pk;
    }
  }
}

// ---------------------------------------------------------------------------
// Kernel 2: flash attention, swapped-operand MFMA, split-KV, no barriers.
// Wave = 16 q-rows x one KV chunk. S^T = mfma(K,Q): lane owns q-row t16;
// softmax = per-lane tree + 2 shuffles. O^T = mfma(V^T, P^T); V^T direct from
// global vt (L2-resident, batch pinned to XCD via bid&7). P via 2KB wave-
// private swizzled LDS. Partials (m,l,O-bf16) combined by kernel 3.
// ---------------------------------------------------------------------------
__global__ __launch_bounds__(256) void attn(
    const u16* __restrict__ qb, const u16* __restrict__ kb,
    const u16* __restrict__ vt, float* __restrict__ out,
    float* __restrict__ ml, u16* __restrict__ ob, int ncl) {
  __shared__ char lds[8192];   // 4 waves x 2KB P buffer
  const int tid = threadIdx.x;
  const int wv = tid >> 6, lane = tid & 63;
  const int g = lane >> 4, t16 = lane & 15;
  const int bid = blockIdx.x;
  const int b = bid & 7;                  // batch == XCD under round-robin
  const int t = (bid >> 3) * 4 + wv;      // 0..128*NCMAX-1
  const int qt = 127 - (t >> ncl);        // heavy tiles first
  const int ch = t & ((1 << ncl) - 1);
  const int CH = 2048 >> ncl;
  const int q0 = qt * 16;
  const int nc = (q0 + 16 + CH - 1) / CH;
  if (ch >= nc) return;

  const size_t bT = (size_t)b * TT;
  const int b64 = b * 64;
  const int wbase = wv * 2048;

  // Q as B-fragment: lane holds col q = q0+t16, k-slice s*32+g*8
  s8v qf[2];
#pragma unroll
  for (int s = 0; s < 2; ++s)
    qf[s] = *(const s8v*)(qb + (bT + q0 + t16) * HH + s * 32 + g * 8);

  float m = -INFINITY, l = 0.f;
  f32x4 zz = {0.f, 0.f, 0.f, 0.f};
  f32x4 oa[4] = {zz, zz, zz, zz};

  const int kv_lo = ch * CH;
  const int kv_hi = min(kv_lo + CH, q0 + 16);

  for (int kv0 = kv_lo; kv0 < kv_hi; kv0 += 64) {
    // K as A-fragments (4 x 16 kv-rows), direct from global (L2)
    s8v kf[4][2];
#pragma unroll
    for (int c = 0; c < 4; ++c)
#pragma unroll
      for (int s = 0; s < 2; ++s)
        kf[c][s] = *(const s8v*)(kb + (bT + kv0 + c * 16 + t16) * HH +
                                 s * 32 + g * 8);
    // S^T: rows kv (g*4+r), cols q (t16)
    f32x4 sa[4] = {zz, zz, zz, zz};
#pragma unroll
    for (int c = 0; c < 4; ++c) {
      sa[c] = MFMA16(kf[c][0], qf[0], sa[c]);
      sa[c] = MFMA16(kf[c][1], qf[1], sa[c]);
    }
    // V^T as A-fragments, direct from global vt (issue early, used after softmax)
    s8v vf[4][2];
#pragma unroll
    for (int c = 0; c < 4; ++c)
#pragma unroll
      for (int s = 0; s < 2; ++s)
        vf[c][s] = *(const s8v*)(vt + (size_t)(b64 + c * 16 + t16) * TT +
                                 kv0 + s * 32 + g * 8);

    if (kv0 + 63 > q0) {   // causal mask (diagonal tile only)
#pragma unroll
      for (int c = 0; c < 4; ++c)
#pragma unroll
        for (int r = 0; r < 4; ++r)
          if (kv0 + c * 16 + g * 4 + r > q0 + t16) sa[c][r] = -INFINITY;
    }

    // online softmax, base-2 domain (q pre-scaled by log2e)
    f32x4 mm = sa[0];
#pragma unroll
    for (int c = 1; c < 4; ++c)
#pragma unroll
      for (int r = 0; r < 4; ++r) mm[r] = fmaxf(mm[r], sa[c][r]);
    float mx = fmaxf(fmaxf(mm[0], mm[1]), fmaxf(mm[2], mm[3]));
    mx = fmaxf(mx, __shfl_xor(mx, 16));
    mx = fmaxf(mx, __shfl_xor(mx, 32));
    if (!__all(mx <= m)) {               // T13 at threshold 0: exact skip
      float mn = fmaxf(m, mx);
      float fr = exp2f(m - mn);          // first tile: exp2(-inf)=0
      m = mn;
      l *= fr;
#pragma unroll
      for (int c = 0; c < 4; ++c) oa[c] *= fr;
    }
    f32x4 ps = zz;
#pragma unroll
    for (int c = 0; c < 4; ++c)
#pragma unroll
      for (int r = 0; r < 4; ++r) {
        float p = exp2f(sa[c][r] - m);
        sa[c][r] = p;
        ps[r] += p;
      }
    float rs = (ps[0] + ps[1]) + (ps[2] + ps[3]);
    rs += __shfl_xor(rs, 16);
    rs += __shfl_xor(rs, 32);
    l += rs;

    // P[q=t16][kv] -> wave-private LDS (bf16, swizzled)
#pragma unroll
    for (int c = 0; c < 4; ++c) {
      u16x4 pk = pack4(sa[c]);
      int off = wbase + ((t16 * 128 + c * 32 + g * 8) ^ ((t16 & 7) << 4));
      *(u16x4*)(lds + off) = pk;
    }
    // O^T += V^T . P^T
#pragma unroll
    for (int ks = 0; ks < 2; ++ks) {
      int off = wbase + ((t16 * 128 + ks * 64 + g * 16) ^ ((t16 & 7) << 4));
      s8v pf = *(const s8v*)(lds + off);
#pragma unroll
      for (int c = 0; c < 4; ++c) oa[c] = MFMA16(vf[c][ks], pf, oa[c]);
    }
  }

  if (nc == 1) {   // direct write: O^T lane holds q=t16, h=c*16+g*4+r
    float inv = 1.0f / l;
#pragma unroll
    for (int c = 0; c < 4; ++c) {
      f4 st;
#pragma unroll
      for (int r = 0; r < 4; ++r) st[r] = oa[c][r] * inv;
      *(f4*)(out + (bT + q0 + t16) * HH + c * 16 + g * 4) = st;
    }
  } else {         // partial: m,l (f32) + unnormalized O (bf16)
    int slot = ((b * 128 + qt) << ncl) + ch;
    if (g == 0) {
      ml[slot * 32 + t16] = m;
      ml[slot * 32 + 16 + t16] = l;
    }
#pragma unroll
    for (int c = 0; c < 4; ++c) {
      u16x4 pk = pack4(oa[c]);
      *(u16x4*)(ob + (size_t)slot * 1024 + t16 * 64 + c * 16 + g * 4) = pk;
    }
  }
}

// ---------------------------------------------------------------------------
// Kernel 3: combine split-KV partials. Thread = (row, 8 cols).
// ---------------------------------------------------------------------------
__global__ __launch_bounds__(256) void combine(
    const float* __restrict__ ml, const u16* __restrict__ ob,
    float* __restrict__ out, int ncl) {
  int gid = blockIdx.x * 256 + threadIdx.x;   // 131072
  int r = gid >> 3, c8 = (gid & 7) << 3;
  int b = r >> 11, q = r & 2047, qt = q >> 4, qi = q & 15;
  int CH = 2048 >> ncl;
  int nc = (qt * 16 + 16 + CH - 1) / CH;
  if (nc < 2) return;                          // attn wrote these directly
  int s0 = (b * 128 + qt) << ncl;
  float M = -INFINITY;
  for (int ch = 0; ch < nc; ++ch) M = fmaxf(M, ml[(s0 + ch) * 32 + qi]);
  float L = 0.f;
  float o[8] = {0, 0, 0, 0, 0, 0, 0, 0};
  for (int ch = 0; ch < nc; ++ch) {
    float w = exp2f(ml[(s0 + ch) * 32 + qi] - M);
    L += ml[(s0 + ch) * 32 + 16 + qi] * w;
    const u16x4* src =
        (const u16x4*)(ob + (size_t)(s0 + ch) * 1024 + qi * 64 + c8);
    u16x4 a = src[0], bv = src[1];
#pragma unroll
    for (int j = 0; j < 4; ++j) {
      o[j] += w * bf2f(a[j]);
      o[4 + j] += w * bf2f(bv[j]);
    }
  }
  float inv = 1.0f / L;
  f4 s1, s2;
#pragma unroll
  for (int j = 0; j < 4; ++j) { s1[j] = o[j] * inv; s2[j] = o[4 + j] * inv; }
  *(f4*)(out + (size_t)r * HH + c8) = s1;
  *(f4*)(out + (size_t)r * HH + c8 + 4) = s2;
}

extern "C" void kernel_launch(void* const* d_in, const int* in_sizes, int n_in,
                              void* d_out, int out_size, void* d_ws, size_t ws_size,
                              hipStream_t stream) {
  (void)in_sizes; (void)n_in; (void)out_size;
  const float* x  = (const float*)d_in[0];
  const float* Wk = (const float*)d_in[1];
  const float* Wq = (const float*)d_in[2];
  const float* Wv = (const float*)d_in[3];
  u16* qb = (u16*)d_ws;
  u16* kb = qb + NQ;
  u16* vt = kb + NQ;
  u16* wt = vt + NQ;                 // 192*768 bf16
  char* endb = (char*)(wt + 192 * CC);
  size_t baseB = (size_t)(3 * NQ + 192 * CC) * 2;
  int ncl = 0;                       // split-KV level chosen by ws capacity
  if (ws_size >= baseB + (size_t)1024 * 8 * 2176) ncl = 3;        // chunk 256
  else if (ws_size >= baseB + (size_t)1024 * 4 * 2176) ncl = 2;   // chunk 512
  int ncmax = 1 << ncl;
  float* mlb = (float*)endb;
  u16* ob = (u16*)(endb + (size_t)1024 * ncmax * 128);
  float* op = (float*)d_out;

  hipLaunchKernelGGL(prep_w, dim3(576), dim3(256), 0, stream, Wk, Wq, Wv, wt);
  hipLaunchKernelGGL(qkv_proj, dim3(NBT / 64), dim3(256), 0, stream,
                     x, wt, qb, kb, vt);
  hipLaunchKernelGGL(attn, dim3(256 * ncmax), dim3(256), 0, stream,
                     qb, kb, vt, op, mlb, ob, ncl);
  if (ncl)
    hipLaunchKernelGGL(combine, dim3(512), dim3(256), 0, stream,
                       mlb, ob, op, ncl);
}